// Round 1
// baseline (148.260 us; speedup 1.0000x reference)
//
#include <hip/hip_runtime.h>

#define NG 512
#define PLANE 512

// ws layout (floats):
//   [0]          : global max key (uint, monotone-mapped float), must be zeroed each call
//   [16 + k*512] : SoA param arrays: A, B, C, MX, MY, L, WR, WG, WB  (9 x 512 floats)

__global__ __launch_bounds__(256) void precompute_kernel(
    const float* __restrict__ mean, const float* __restrict__ alpha,
    const float* __restrict__ scale, const float* __restrict__ theta,
    const float* __restrict__ rgb, float* __restrict__ ws) {
    int i = blockIdx.x * blockDim.x + threadIdx.x;
    if (i >= NG) return;

    const float TWO_PI = 6.283185307179586f;
    float ta = TWO_PI * theta[i];
    float c = cosf(ta), s = sinf(ta);
    float sx = scale[2 * i], sy = scale[2 * i + 1];

    // M2 = rot @ smat @ smat^T  (mimic reference f32 order)
    float m200 = (c * sx) * sx;
    float m201 = (-(s * sy)) * sy;
    float m210 = (s * sx) * sx;
    float m211 = (c * sy) * sy;
    // cov = M2 @ rot^T,  rot^T = [[c, s], [-s, c]]
    float a   = m200 * c + m201 * (-s);
    float b01 = m200 * s + m201 * c;
    float b10 = m210 * c + m211 * (-s);
    float d   = m210 * s + m211 * c;

    float det = a * d - b01 * b10;
    float inv00 = d / det;
    float inv01 = -b01 / det;
    float inv10 = -b10 / det;
    float inv11 = a / det;

    float norm = 1.0f / (TWO_PI * sqrtf(det));  // 1/(2*pi*sqrt(det))

    const float K = -0.5f * 1.4426950408889634f;  // -0.5 * log2(e)

    float* A  = ws + 16;
    float* B  = A + NG;
    float* C  = B + NG;
    float* MX = C + NG;
    float* MY = MX + NG;
    float* Lg = MY + NG;
    float* WR = Lg + NG;
    float* WG = WR + NG;
    float* WB = WG + NG;

    A[i]  = K * inv00;
    B[i]  = K * (inv01 + inv10);
    C[i]  = K * inv11;
    MX[i] = mean[2 * i];
    MY[i] = mean[2 * i + 1];
    Lg[i] = log2f(norm);
    float w = alpha[i] * norm;
    WR[i] = rgb[3 * i] * w;
    WG[i] = rgb[3 * i + 1] * w;
    WB[i] = rgb[3 * i + 2] * w;
}

// Each thread: 4 consecutive pixels in one row. 65536 threads total.
__global__ __launch_bounds__(256) void splat_kernel(
    const float* __restrict__ pixels, const float* __restrict__ P,
    float* __restrict__ out, unsigned* __restrict__ maxkey) {
    int g = blockIdx.x * 256 + threadIdx.x;
    int h = g >> 7;              // row 0..511
    int w0 = (g & 127) << 2;     // col 0,4,...,508
    int pbase = h * PLANE + w0;

    float x0 = pixels[2 * (pbase + 0) + 0];
    float x1 = pixels[2 * (pbase + 1) + 0];
    float x2 = pixels[2 * (pbase + 2) + 0];
    float x3 = pixels[2 * (pbase + 3) + 0];
    float y  = pixels[2 * pbase + 1];

    const float* A  = P;
    const float* B  = A + NG;
    const float* C  = B + NG;
    const float* MX = C + NG;
    const float* MY = MX + NG;
    const float* Lg = MY + NG;
    const float* WR = Lg + NG;
    const float* WG = WR + NG;
    const float* WB = WG + NG;

    float ar0 = 0.f, ag0 = 0.f, ab0 = 0.f;
    float ar1 = 0.f, ag1 = 0.f, ab1 = 0.f;
    float ar2 = 0.f, ag2 = 0.f, ab2 = 0.f;
    float ar3 = 0.f, ag3 = 0.f, ab3 = 0.f;
    float m = -1e30f;

#pragma unroll 4
    for (int n = 0; n < NG; ++n) {
        float a  = A[n];
        float b  = B[n];
        float cc = C[n];
        float mx = MX[n];
        float my = MY[n];

        float dy   = y - my;
        float bdy  = b * dy;
        float cdy2 = cc * (dy * dy);

        float dx0 = x0 - mx, dx1 = x1 - mx, dx2 = x2 - mx, dx3 = x3 - mx;
        float q0 = fmaf(fmaf(a, dx0, bdy), dx0, cdy2);
        float q1 = fmaf(fmaf(a, dx1, bdy), dx1, cdy2);
        float q2 = fmaf(fmaf(a, dx2, bdy), dx2, cdy2);
        float q3 = fmaf(fmaf(a, dx3, bdy), dx3, cdy2);

        float e0 = exp2f(q0);
        float e1 = exp2f(q1);
        float e2 = exp2f(q2);
        float e3 = exp2f(q3);

        float wr = WR[n], wg = WG[n], wb = WB[n];
        ar0 = fmaf(e0, wr, ar0); ag0 = fmaf(e0, wg, ag0); ab0 = fmaf(e0, wb, ab0);
        ar1 = fmaf(e1, wr, ar1); ag1 = fmaf(e1, wg, ag1); ab1 = fmaf(e1, wb, ab1);
        ar2 = fmaf(e2, wr, ar2); ag2 = fmaf(e2, wg, ag2); ab2 = fmaf(e2, wb, ab2);
        ar3 = fmaf(e3, wr, ar3); ag3 = fmaf(e3, wg, ag3); ab3 = fmaf(e3, wb, ab3);

        float qm = fmaxf(fmaxf(q0, q1), fmaxf(q2, q3));
        m = fmaxf(m, qm + Lg[n]);  // log2(prob) max tracking
    }

    // store 12 consecutive floats (3 x float4, 16B-aligned: pbase%4==0)
    float* o = out + (size_t)pbase * 3;
    float4 v0 = make_float4(ar0, ag0, ab0, ar1);
    float4 v1 = make_float4(ag1, ab1, ar2, ag2);
    float4 v2 = make_float4(ab2, ar3, ag3, ab3);
    *reinterpret_cast<float4*>(o + 0) = v0;
    *reinterpret_cast<float4*>(o + 4) = v1;
    *reinterpret_cast<float4*>(o + 8) = v2;

    // block max reduction -> one atomic per block
#pragma unroll
    for (int off = 32; off > 0; off >>= 1)
        m = fmaxf(m, __shfl_xor(m, off));
    __shared__ float sm[4];
    if ((threadIdx.x & 63) == 0) sm[threadIdx.x >> 6] = m;
    __syncthreads();
    if (threadIdx.x == 0) {
        float mm = fmaxf(fmaxf(sm[0], sm[1]), fmaxf(sm[2], sm[3]));
        unsigned bu = __float_as_uint(mm);
        unsigned key = bu ^ (unsigned)(((int)bu >> 31) | 0x80000000);
        atomicMax(maxkey, key);
    }
}

__device__ __forceinline__ float sigmoidf_fast(float x) {
    return 1.0f / (1.0f + exp2f(-1.4426950408889634f * x));
}

__global__ __launch_bounds__(256) void finalize_kernel(
    float* __restrict__ out, const unsigned* __restrict__ maxkey) {
    unsigned k = *maxkey;
    unsigned bu = (k & 0x80000000u) ? (k ^ 0x80000000u) : ~k;
    float tmax = __uint_as_float(bu);
    float invmax = exp2f(-tmax);  // 1 / max(prob)

    int i = blockIdx.x * 256 + threadIdx.x;
    float4* p = reinterpret_cast<float4*>(out) + i;
    float4 v = *p;
    v.x = sigmoidf_fast(v.x * invmax);
    v.y = sigmoidf_fast(v.y * invmax);
    v.z = sigmoidf_fast(v.z * invmax);
    v.w = sigmoidf_fast(v.w * invmax);
    *p = v;
}

extern "C" void kernel_launch(void* const* d_in, const int* in_sizes, int n_in,
                              void* d_out, int out_size, void* d_ws, size_t ws_size,
                              hipStream_t stream) {
    const float* mean   = (const float*)d_in[0];
    const float* alpha  = (const float*)d_in[1];
    const float* scale  = (const float*)d_in[2];
    const float* theta  = (const float*)d_in[3];
    const float* rgb    = (const float*)d_in[4];
    const float* pixels = (const float*)d_in[5];
    float* ws = (float*)d_ws;
    float* out = (float*)d_out;

    // zero the max-key slot (ws is poisoned 0xAA before every launch)
    hipMemsetAsync(d_ws, 0, 64, stream);

    precompute_kernel<<<2, 256, 0, stream>>>(mean, alpha, scale, theta, rgb, ws);

    // 512*512 pixels / 4 per thread = 65536 threads = 256 blocks
    splat_kernel<<<256, 256, 0, stream>>>(pixels, ws + 16, out, (unsigned*)ws);

    // 786432 floats / 4 per thread = 196608 threads = 768 blocks
    finalize_kernel<<<768, 256, 0, stream>>>(out, (const unsigned*)ws);
}

// Round 3
// 143.327 us; speedup vs baseline: 1.0344x; 1.0344x over previous
//
#include <hip/hip_runtime.h>

#define NG 512
#define PLANE 512

// ws layout (floats):
//   [0]          : global max key (monotone uint-mapped float) -- memset to 0 each call
//   [16 + k*512] : SoA param arrays: A, B, C, MX, MY, WR, WG, WB (8 x 512)

__device__ __forceinline__ unsigned float_key(float f) {
    unsigned bu = __float_as_uint(f);
    return bu ^ (unsigned)(((int)bu >> 31) | 0x80000000);
}

// One thread per (gaussian, row): recompute params (no sync needed), find the
// exact discrete max of t = log2(prob) along this row (concave parabola in x
// -> vertex +/-1 lattice candidates), reduce to a single global atomicMax.
// Threads with row==0 also publish the SoA params for the splat kernel.
__global__ __launch_bounds__(256) void prep_kernel(
    const float* __restrict__ mean, const float* __restrict__ alpha,
    const float* __restrict__ scale, const float* __restrict__ theta,
    const float* __restrict__ rgb, const float* __restrict__ pixels,
    float* __restrict__ ws) {
    int gid = blockIdx.x * 256 + threadIdx.x;   // 0 .. 262143
    int n   = gid >> 9;
    int row = gid & 511;

    const float TWO_PI = 6.283185307179586f;
    float ta = TWO_PI * theta[n];
    float c = cosf(ta), s = sinf(ta);
    float sx = scale[2 * n], sy = scale[2 * n + 1];

    // cov = rot @ smat @ smat^T @ rot^T (reference f32 order)
    float m200 = (c * sx) * sx;
    float m201 = (-(s * sy)) * sy;
    float m210 = (s * sx) * sx;
    float m211 = (c * sy) * sy;
    float a   = m200 * c + m201 * (-s);
    float b01 = m200 * s + m201 * c;
    float b10 = m210 * c + m211 * (-s);
    float d   = m210 * s + m211 * c;

    float det = a * d - b01 * b10;
    float inv00 = d / det;
    float inv01 = -b01 / det;
    float inv10 = -b10 / det;
    float inv11 = a / det;

    float norm = 1.0f / (TWO_PI * sqrtf(det));
    const float K = -0.5f * 1.4426950408889634f;  // -0.5 * log2(e)

    float A_ = K * inv00;
    float B_ = K * (inv01 + inv10);
    float C_ = K * inv11;
    float mx = mean[2 * n], my = mean[2 * n + 1];
    float Lg = log2f(norm);

    if (row == 0) {
        float* A  = ws + 16;
        A[n]            = A_;
        A[n + NG]       = B_;
        A[n + 2 * NG]   = C_;
        A[n + 3 * NG]   = mx;
        A[n + 4 * NG]   = my;
        float w = alpha[n] * norm;
        A[n + 5 * NG]   = rgb[3 * n] * w;
        A[n + 6 * NG]   = rgb[3 * n + 1] * w;
        A[n + 7 * NG]   = rgb[3 * n + 2] * w;
    }

    // row's y coordinate
    float y  = pixels[2 * (row * PLANE) + 1];
    float dy = y - my;
    float bdy  = B_ * dy;
    float cdy2 = C_ * (dy * dy);

    // vertex of the concave parabola t(dx): dx* = -B*dy/(2A)
    float xstar = mx - bdy / (2.0f * A_);
    float xs = fminf(fmaxf(xstar, 0.0f), 1.0f);   // NaN-safe clamp
    int i1 = (int)floorf(xs * 511.0f);
    i1 = max(0, min(i1, 510));

    float t = -1e30f;
#pragma unroll
    for (int kk = -1; kk <= 2; ++kk) {
        int i = max(0, min(i1 + kk, 511));
        float x = pixels[2 * (row * PLANE + i)];
        float dx = x - mx;
        float q = fmaf(fmaf(A_, dx, bdy), dx, cdy2);
        t = fmaxf(t, q);
    }
    t += Lg;

    // wave -> block -> global max
#pragma unroll
    for (int off = 32; off > 0; off >>= 1)
        t = fmaxf(t, __shfl_xor(t, off));
    __shared__ float sm[4];
    if ((threadIdx.x & 63) == 0) sm[threadIdx.x >> 6] = t;
    __syncthreads();
    if (threadIdx.x == 0) {
        float mm = fmaxf(fmaxf(sm[0], sm[1]), fmaxf(sm[2], sm[3]));
        atomicMax((unsigned*)ws, float_key(mm));
    }
}

// 2 px/thread, 512 blocks x 256 threads = 2 blocks/CU = 2 waves/SIMD.
// Max is already known -> no max tracking in the loop, sigmoid fused here.
__global__ __launch_bounds__(256, 2) void splat_kernel(
    const float* __restrict__ pixels, const float* __restrict__ ws,
    float* __restrict__ out) {
    unsigned k = *(const unsigned*)ws;
    unsigned bu = (k & 0x80000000u) ? (k ^ 0x80000000u) : ~k;
    float tmax = __uint_as_float(bu);
    float invmax = exp2f(-tmax);  // 1 / max(prob)

    const unsigned gid = blockIdx.x * 256 + threadIdx.x;
    const int row  = gid >> 8;
    const int col0 = (gid & 255) << 1;
    const int pbase = row * PLANE + col0;

    const float x0 = pixels[2 * pbase + 0];
    const float x1 = pixels[2 * pbase + 2];
    const float y  = pixels[2 * pbase + 1];

    const float* A  = ws + 16;
    const float* B  = A + NG;
    const float* C  = B + NG;
    const float* MX = C + NG;
    const float* MY = MX + NG;
    const float* WR = MY + NG;
    const float* WG = WR + NG;
    const float* WB = WG + NG;

    float ar0 = 0.f, ag0 = 0.f, ab0 = 0.f;
    float ar1 = 0.f, ag1 = 0.f, ab1 = 0.f;

#pragma unroll 4
    for (int n = 0; n < NG; ++n) {
        float a  = A[n];
        float b  = B[n];
        float cc = C[n];
        float mx = MX[n];
        float my = MY[n];

        float dy   = y - my;
        float bdy  = b * dy;
        float cdy2 = cc * (dy * dy);

        float dx0 = x0 - mx, dx1 = x1 - mx;
        float q0 = fmaf(fmaf(a, dx0, bdy), dx0, cdy2);
        float q1 = fmaf(fmaf(a, dx1, bdy), dx1, cdy2);

        float e0 = exp2f(q0);
        float e1 = exp2f(q1);

        float wr = WR[n], wg = WG[n], wb = WB[n];
        ar0 = fmaf(e0, wr, ar0); ag0 = fmaf(e0, wg, ag0); ab0 = fmaf(e0, wb, ab0);
        ar1 = fmaf(e1, wr, ar1); ag1 = fmaf(e1, wg, ag1); ab1 = fmaf(e1, wb, ab1);
    }

    const float KE = 1.4426950408889634f;  // log2(e)
    float v0 = ar0 * invmax, v1 = ag0 * invmax, v2 = ab0 * invmax;
    float v3 = ar1 * invmax, v4 = ag1 * invmax, v5 = ab1 * invmax;
    v0 = 1.0f / (1.0f + exp2f(-KE * v0));
    v1 = 1.0f / (1.0f + exp2f(-KE * v1));
    v2 = 1.0f / (1.0f + exp2f(-KE * v2));
    v3 = 1.0f / (1.0f + exp2f(-KE * v3));
    v4 = 1.0f / (1.0f + exp2f(-KE * v4));
    v5 = 1.0f / (1.0f + exp2f(-KE * v5));

    float* o = out + (size_t)pbase * 3;  // 6 consecutive floats, 8B-aligned
    *reinterpret_cast<float2*>(o + 0) = make_float2(v0, v1);
    *reinterpret_cast<float2*>(o + 2) = make_float2(v2, v3);
    *reinterpret_cast<float2*>(o + 4) = make_float2(v4, v5);
}

extern "C" void kernel_launch(void* const* d_in, const int* in_sizes, int n_in,
                              void* d_out, int out_size, void* d_ws, size_t ws_size,
                              hipStream_t stream) {
    const float* mean   = (const float*)d_in[0];
    const float* alpha  = (const float*)d_in[1];
    const float* scale  = (const float*)d_in[2];
    const float* theta  = (const float*)d_in[3];
    const float* rgb    = (const float*)d_in[4];
    const float* pixels = (const float*)d_in[5];
    float* out = (float*)d_out;
    float* ws  = (float*)d_ws;

    hipMemsetAsync(d_ws, 0, 64, stream);

    // 512 gaussians x 512 rows = 262144 threads
    prep_kernel<<<1024, 256, 0, stream>>>(mean, alpha, scale, theta, rgb, pixels, ws);

    // 512*512 px / 2 per thread = 131072 threads
    splat_kernel<<<512, 256, 0, stream>>>(pixels, ws, out);
}

// Round 4
// 125.795 us; speedup vs baseline: 1.1786x; 1.1394x over previous
//
#include <hip/hip_runtime.h>

#define NG 512
#define PLANE 512

// ws layout (float index):
//   [16 .. 16+8*513)   : packed params, 8 floats per gaussian:
//                        {A, B, C, mx, my, wr, wg, wb}  (entry 512 = prefetch pad, never computed with)
//   [4352 .. 4864)     : per-gaussian max slots t[n] = max log2(prob_n)  (512 floats)
#define PRM_OFF  16
#define SLOT_OFF 4352

// One wave per gaussian: compute params (all lanes redundantly, HW trig/rcp),
// lane 0 publishes packed params; lanes scan 512 rows (8 rows/lane) for the
// exact discrete max of t = log2(prob) (concave parabola in x per row ->
// vertex +/- lattice candidates), shfl-reduce, lane 0 stores the slot.
__global__ __launch_bounds__(256) void prep_kernel(
    const float* __restrict__ mean, const float* __restrict__ alpha,
    const float* __restrict__ scale, const float* __restrict__ theta,
    const float* __restrict__ rgb, const float* __restrict__ pixels,
    float* __restrict__ ws) {
    const int n    = (blockIdx.x * 256 + threadIdx.x) >> 6;   // 0..511
    const int lane = threadIdx.x & 63;

    const float TWO_PI = 6.283185307179586f;
    float th = theta[n];
    float c = __builtin_amdgcn_cosf(th);   // cos(2*pi*th): v_cos takes revolutions
    float s = __builtin_amdgcn_sinf(th);
    float sx = scale[2 * n], sy = scale[2 * n + 1];

    // cov = rot @ smat @ smat^T @ rot^T (reference f32 order)
    float m200 = (c * sx) * sx;
    float m201 = (-(s * sy)) * sy;
    float m210 = (s * sx) * sx;
    float m211 = (c * sy) * sy;
    float a   = m200 * c + m201 * (-s);
    float b01 = m200 * s + m201 * c;
    float b10 = m210 * c + m211 * (-s);
    float d   = m210 * s + m211 * c;

    float det = a * d - b01 * b10;
    float rdet = __builtin_amdgcn_rcpf(det);
    float inv00 = d * rdet;
    float inv01 = -b01 * rdet;
    float inv10 = -b10 * rdet;
    float inv11 = a * rdet;

    float norm = __builtin_amdgcn_rcpf(TWO_PI * __builtin_amdgcn_sqrtf(det));
    const float K = -0.5f * 1.4426950408889634f;  // -0.5 * log2(e)

    float A_ = K * inv00;
    float B_ = K * (inv01 + inv10);
    float C_ = K * inv11;
    float mx = mean[2 * n], my = mean[2 * n + 1];
    // Lg = log2(norm) = -log2(2*pi) - 0.5*log2(det)
    float Lg = fmaf(-0.5f, __builtin_amdgcn_logf(det), -2.651496129472319f);

    if (lane == 0) {
        float w = alpha[n] * norm;
        float4* p = (float4*)(ws + PRM_OFF + 8 * n);
        p[0] = make_float4(A_, B_, C_, mx);
        p[1] = make_float4(my, w * rgb[3 * n], w * rgb[3 * n + 1], w * rgb[3 * n + 2]);
    }

    // row scan: 8 rows per lane
    float inv2A = __builtin_amdgcn_rcpf(2.0f * A_);
    float t = -1e30f;
#pragma unroll
    for (int k = 0; k < 8; ++k) {
        int r = lane + (k << 6);
        float y  = pixels[(r << 10) + 1];
        float dy = y - my;
        float bdy  = B_ * dy;
        float cdy2 = C_ * (dy * dy);
        float xstar = mx - bdy * inv2A;
        float xs = fminf(fmaxf(xstar, 0.0f), 1.0f);   // NaN-safe clamp
        int i1 = min((int)(xs * 511.0f), 510);
#pragma unroll
        for (int kk = -1; kk <= 2; ++kk) {
            int i = max(0, min(i1 + kk, 511));
            float x = pixels[(r << 10) + (i << 1)];
            float dx = x - mx;
            float q = fmaf(fmaf(A_, dx, bdy), dx, cdy2);
            t = fmaxf(t, q);
        }
    }
    t += Lg;
#pragma unroll
    for (int off = 32; off > 0; off >>= 1)
        t = fmaxf(t, __shfl_xor(t, off));
    if (lane == 0) ws[SLOT_OFF + n] = t;
}

// 2 px/thread, 512 blocks x 256 threads (2 waves/SIMD). Params via packed
// 32B scalar loads with 1-iter rotate prefetch; raw v_exp_f32; fused sigmoid.
__global__ __launch_bounds__(256, 2) void splat_kernel(
    const float* __restrict__ pixels, const float* __restrict__ ws,
    float* __restrict__ out) {
    const unsigned gid = blockIdx.x * 256 + threadIdx.x;
    const int row  = gid >> 8;
    const int col0 = (gid & 255) << 1;
    const int pbase = row * PLANE + col0;

    // one dwordx4: {x0, y, x1, y}
    float4 pix = *reinterpret_cast<const float4*>(pixels + 2 * pbase);
    const float x0 = pix.x, y = pix.y, x1 = pix.z;

    const float4* prm4 = reinterpret_cast<const float4*>(ws + PRM_OFF);

    float ar0 = 0.f, ag0 = 0.f, ab0 = 0.f;
    float ar1 = 0.f, ag1 = 0.f, ab1 = 0.f;

    float4 pa = prm4[0];
    float4 pb = prm4[1];
#pragma unroll 4
    for (int n = 0; n < NG; ++n) {
        float4 na = prm4[2 * n + 2];   // prefetch next (n=511 reads pad entry)
        float4 nb = prm4[2 * n + 3];

        float a = pa.x, b = pa.y, cc = pa.z, mx = pa.w;
        float my = pb.x, wr = pb.y, wg = pb.z, wb = pb.w;

        float dy   = y - my;
        float bdy  = b * dy;
        float cdy2 = cc * (dy * dy);

        float dx0 = x0 - mx, dx1 = x1 - mx;
        float q0 = fmaf(fmaf(a, dx0, bdy), dx0, cdy2);
        float q1 = fmaf(fmaf(a, dx1, bdy), dx1, cdy2);

        float e0 = __builtin_amdgcn_exp2f(q0);
        float e1 = __builtin_amdgcn_exp2f(q1);

        ar0 = fmaf(e0, wr, ar0); ag0 = fmaf(e0, wg, ag0); ab0 = fmaf(e0, wb, ab0);
        ar1 = fmaf(e1, wr, ar1); ag1 = fmaf(e1, wg, ag1); ab1 = fmaf(e1, wb, ab1);

        pa = na; pb = nb;
    }

    // reduce the 512 per-gaussian max slots: 8 per lane + shfl tree
    {
        const int lane = threadIdx.x & 63;
        const float4* sl = reinterpret_cast<const float4*>(ws + SLOT_OFF) + 2 * lane;
        float4 s0 = sl[0], s1 = sl[1];
        float m = fmaxf(fmaxf(fmaxf(s0.x, s0.y), fmaxf(s0.z, s0.w)),
                        fmaxf(fmaxf(s1.x, s1.y), fmaxf(s1.z, s1.w)));
#pragma unroll
        for (int off = 32; off > 0; off >>= 1)
            m = fmaxf(m, __shfl_xor(m, off));
        float invmax = __builtin_amdgcn_exp2f(-m);   // 1 / max(prob)

        const float KE = 1.4426950408889634f;  // log2(e)
        float v0 = ar0 * invmax, v1 = ag0 * invmax, v2 = ab0 * invmax;
        float v3 = ar1 * invmax, v4 = ag1 * invmax, v5 = ab1 * invmax;
        v0 = __builtin_amdgcn_rcpf(1.0f + __builtin_amdgcn_exp2f(-KE * v0));
        v1 = __builtin_amdgcn_rcpf(1.0f + __builtin_amdgcn_exp2f(-KE * v1));
        v2 = __builtin_amdgcn_rcpf(1.0f + __builtin_amdgcn_exp2f(-KE * v2));
        v3 = __builtin_amdgcn_rcpf(1.0f + __builtin_amdgcn_exp2f(-KE * v3));
        v4 = __builtin_amdgcn_rcpf(1.0f + __builtin_amdgcn_exp2f(-KE * v4));
        v5 = __builtin_amdgcn_rcpf(1.0f + __builtin_amdgcn_exp2f(-KE * v5));

        float* o = out + (size_t)pbase * 3;  // 6 consecutive floats, 8B-aligned
        *reinterpret_cast<float2*>(o + 0) = make_float2(v0, v1);
        *reinterpret_cast<float2*>(o + 2) = make_float2(v2, v3);
        *reinterpret_cast<float2*>(o + 4) = make_float2(v4, v5);
    }
}

extern "C" void kernel_launch(void* const* d_in, const int* in_sizes, int n_in,
                              void* d_out, int out_size, void* d_ws, size_t ws_size,
                              hipStream_t stream) {
    const float* mean   = (const float*)d_in[0];
    const float* alpha  = (const float*)d_in[1];
    const float* scale  = (const float*)d_in[2];
    const float* theta  = (const float*)d_in[3];
    const float* rgb    = (const float*)d_in[4];
    const float* pixels = (const float*)d_in[5];
    float* out = (float*)d_out;
    float* ws  = (float*)d_ws;

    // 512 waves (1 per gaussian) = 128 blocks
    prep_kernel<<<128, 256, 0, stream>>>(mean, alpha, scale, theta, rgb, pixels, ws);

    // 512*512 px / 2 per thread = 131072 threads = 512 blocks
    splat_kernel<<<512, 256, 0, stream>>>(pixels, ws, out);
}